// Round 2
// baseline (812.286 us; speedup 1.0000x reference)
//
#include <hip/hip_runtime.h>

// MaxPool2d k=2 s=2 valid, NCHW fp32.
// In : (32, 96, 224, 224)  -> 154,140,672 floats (616.6 MB)
// Out: (32, 96, 112, 112)  ->  38,535,168 floats (154.1 MB)
//
// Streaming kernel, roofline ~122 us at 6.3 TB/s.
//
// v2b: persistent-ish grid with exact-divisible pointer walk.
//   - T = 12544 blocks x 256 thr = 3,211,264 threads
//   - n_out2 = 19,267,584 float2 outputs = T * 6 exactly -> 6 iters/thread,
//     no tail, no bounds checks.
//   - Grid stride T float2 = T/56 = 57,344 output rows = 512 whole channels,
//     so col2 and oh are LOOP-INVARIANT: one div/mod pair per thread (was one
//     per output), and the loop body is a constant pointer advance.
//   - Full unroll -> 12 independent 16B loads in flight per thread (MLP),
//     instead of 2 loads then thread-exit.
//   - Per-instruction access pattern unchanged vs v1: 16 B/lane contiguous
//     loads (1 KB/wave), 8 B/lane contiguous stores. Cannot regress coalescing.
//   - Nontemporal stores via native ext_vector_type (HIP float2 is a class
//     type the builtin rejects — that was v2's compile error).

#define IN_W    224
#define IN_HW   (224 * 224)   // 50176
#define OUT_W2  56            // float2 per output row
#define OUT_H   112
#define BLOCKS  12544
#define TPB     256
#define ITERS   6
#define NTHREADS (BLOCKS * TPB)          // 3,211,264
#define NC_STEP  512                     // channels advanced per iteration
                                         // = NTHREADS / 56 / 112

typedef float f32x2 __attribute__((ext_vector_type(2)));

__global__ __launch_bounds__(256) void maxpool2x2_kernel(
    const float* __restrict__ in, float* __restrict__ out) {
  int q = blockIdx.x * TPB + threadIdx.x;  // first output float2 index

  // Loop-invariant decomposition (stride is divisible by 56 and 56*112).
  int col2 = q % OUT_W2;
  int row  = q / OUT_W2;      // flattened nc*112 + oh, < 57,344
  int oh   = row % OUT_H;
  int nc0  = row / OUT_H;     // < 512

  const float* p = in + (size_t)nc0 * IN_HW + (size_t)(2 * oh) * IN_W
                      + (size_t)col2 * 4;
  f32x2* o = (f32x2*)out + q;

#pragma unroll
  for (int i = 0; i < ITERS; ++i) {
    float4 a = *(const float4*)(p);         // input row 2*oh,   4 cols
    float4 b = *(const float4*)(p + IN_W);  // input row 2*oh+1, 4 cols

    f32x2 r;
    r.x = fmaxf(fmaxf(a.x, a.y), fmaxf(b.x, b.y));
    r.y = fmaxf(fmaxf(a.z, a.w), fmaxf(b.z, b.w));
    __builtin_nontemporal_store(r, o);

    p += (size_t)NC_STEP * IN_HW;  // +512 channels
    o += NTHREADS;                 // +T float2 outputs
  }
}

extern "C" void kernel_launch(void* const* d_in, const int* in_sizes, int n_in,
                              void* d_out, int out_size, void* d_ws, size_t ws_size,
                              hipStream_t stream) {
  const float* in = (const float*)d_in[0];
  float* out = (float*)d_out;
  // Fixed-shape problem: out_size/2 == 19,267,584 == BLOCKS*TPB*ITERS.
  maxpool2x2_kernel<<<BLOCKS, TPB, 0, stream>>>(in, out);
}

// Round 3
// 800.141 us; speedup vs baseline: 1.0152x; 1.0152x over previous
//
#include <hip/hip_runtime.h>

// MaxPool2d k=2 s=2 valid, NCHW fp32.
// In : (32, 96, 224, 224)  -> 154,140,672 floats (616.6 MB)
// Out: (32, 96, 112, 112)  ->  38,535,168 floats (154.1 MB)
//
// Pure streaming op: each input byte read exactly once. Roofline ~122 us
// at 6.3 TB/s for 770.7 MB total traffic.
//
// v3: block-contiguous supertile walk + nontemporal LOADS.
//   - 12544 blocks x 256 thr; each block owns 1536 consecutive float2
//     outputs (6 iters x 256). Iteration stride is 256 float2 = 8 KB of
//     input -> all 6 iterations of a wave stay within a handful of pages
//     (v2b's stride was 102.8 MB of input per iteration -> TLB spread).
//   - Per-instruction pattern unchanged: lanes contiguous, 16 B/lane
//     float4 loads (1 KB/wave), 8 B/lane float2 stores.
//   - Full unroll -> 12 independent 16 B loads in flight per thread.
//   - Nontemporal on BOTH loads and stores: stream-once data, never
//     reused -> no L2/L3 allocation. (v2b had nt stores only.)
//   - Addressing recomputed per iteration (div/mod by 56/112 via magic
//     mul) — VALU is ~5 us of capacity total, a non-factor.

#define IN_W    224
#define IN_HW   (224 * 224)   // 50176
#define OUT_W2  56            // float2 per output row
#define OUT_H   112
#define TPB     256
#define ITERS   6
#define BLOCKS  12544         // 19,267,584 float2 / (256*6) exactly

typedef float f32x2 __attribute__((ext_vector_type(2)));
typedef float f32x4 __attribute__((ext_vector_type(4)));

__global__ __launch_bounds__(256) void maxpool2x2_kernel(
    const float* __restrict__ in, float* __restrict__ out) {
  int q0 = blockIdx.x * (TPB * ITERS) + threadIdx.x;

#pragma unroll
  for (int i = 0; i < ITERS; ++i) {
    int q    = q0 + i * TPB;
    int col2 = q % OUT_W2;
    int row  = q / OUT_W2;      // flattened nc*112 + oh
    int oh   = row % OUT_H;
    int nc   = row / OUT_H;

    const float* p = in + (size_t)nc * IN_HW + (size_t)(2 * oh) * IN_W
                        + (size_t)col2 * 4;

    f32x4 a = __builtin_nontemporal_load((const f32x4*)p);          // row 2*oh
    f32x4 b = __builtin_nontemporal_load((const f32x4*)(p + IN_W)); // row 2*oh+1

    f32x2 r;
    r.x = fmaxf(fmaxf(a.x, a.y), fmaxf(b.x, b.y));
    r.y = fmaxf(fmaxf(a.z, a.w), fmaxf(b.z, b.w));
    __builtin_nontemporal_store(r, (f32x2*)out + q);
  }
}

extern "C" void kernel_launch(void* const* d_in, const int* in_sizes, int n_in,
                              void* d_out, int out_size, void* d_ws, size_t ws_size,
                              hipStream_t stream) {
  const float* in = (const float*)d_in[0];
  float* out = (float*)d_out;
  // Fixed-shape problem: out_size/2 == 19,267,584 == BLOCKS*TPB*ITERS.
  maxpool2x2_kernel<<<BLOCKS, TPB, 0, stream>>>(in, out);
}